// Round 13
// baseline (1047.020 us; speedup 1.0000x reference)
//
#include <hip/hip_runtime.h>
#include <hip/hip_bf16.h>

// Problem constants
#define BATCH   64
#define SEQ     512
#define IN0     512
#define HID     128
#define G3      384   // 3*HID
#define NLAY    5
#define CHUNK   8     // handoff granularity (one release/acquire per CHUNK steps)

typedef _Float16 f16x8 __attribute__((ext_vector_type(8)));
typedef float    f32x4 __attribute__((ext_vector_type(4)));

static __device__ __forceinline__ float sigf(float x) {
    return __builtin_amdgcn_rcpf(1.f + __expf(-x));
}
static __device__ __forceinline__ float tanh_fast(float x) {
    // exp(-2|x|) = exp2(|x| * -2*log2(e)); single mul + v_exp
    const float e = exp2f(fabsf(x) * -2.885390082f);
    return copysignf((1.f - e) * __builtin_amdgcn_rcpf(1.f + e), x);
}

// ---------------------------------------------------------------------------
// gemm_gx (MFMA): gx0[32768][384] = x[32768][512] @ w_ih0[384][512]^T + b_ih0
// (unchanged)
// ---------------------------------------------------------------------------
__global__ __launch_bounds__(256) void gemm_gx(const float* __restrict__ A,
                                               const float* __restrict__ W,
                                               const float* __restrict__ bias,
                                               float* __restrict__ gx)
{
    __shared__ __align__(16) _Float16 As[64][40];   // [m][k0..31], pad 40 (80B rows)
    __shared__ __align__(16) _Float16 Bs[64][40];   // [n][k0..31]

    const int tid  = threadIdx.x;
    const int lane = tid & 63;
    const int wv   = tid >> 6;          // m-subtile
    const int n16  = lane & 15;
    const int quad = lane >> 4;
    const int row0 = blockIdx.x * 64;
    const int col0 = blockIdx.y * 64;
    const int r    = tid >> 2;          // staging row 0..63
    const int kc   = (tid & 3) * 8;     // staging k offset 0,8,16,24

    f32x4 acc[4];
    #pragma unroll
    for (int nt = 0; nt < 4; nt++) acc[nt] = (f32x4){0.f, 0.f, 0.f, 0.f};

    for (int k0 = 0; k0 < IN0; k0 += 32) {
        // ---- stage A (x) tile, f32 -> f16 ----
        {
            const float* Ap = A + (size_t)(row0 + r) * IN0 + k0 + kc;
            float4 a0 = *(const float4*)(Ap);
            float4 a1 = *(const float4*)(Ap + 4);
            f16x8 v;
            v[0] = (_Float16)a0.x; v[1] = (_Float16)a0.y; v[2] = (_Float16)a0.z; v[3] = (_Float16)a0.w;
            v[4] = (_Float16)a1.x; v[5] = (_Float16)a1.y; v[6] = (_Float16)a1.z; v[7] = (_Float16)a1.w;
            *(f16x8*)&As[r][kc] = v;
        }
        // ---- stage B (w_ih0) tile ----
        {
            const float* Wp = W + (size_t)(col0 + r) * IN0 + k0 + kc;
            float4 b0 = *(const float4*)(Wp);
            float4 b1 = *(const float4*)(Wp + 4);
            f16x8 v;
            v[0] = (_Float16)b0.x; v[1] = (_Float16)b0.y; v[2] = (_Float16)b0.z; v[3] = (_Float16)b0.w;
            v[4] = (_Float16)b1.x; v[5] = (_Float16)b1.y; v[6] = (_Float16)b1.z; v[7] = (_Float16)b1.w;
            *(f16x8*)&Bs[r][kc] = v;
        }
        __syncthreads();

        const f16x8 af = *(const f16x8*)&As[wv * 16 + n16][quad * 8];
        #pragma unroll
        for (int nt = 0; nt < 4; nt++) {
            const f16x8 bfr = *(const f16x8*)&Bs[nt * 16 + n16][quad * 8];
            acc[nt] = __builtin_amdgcn_mfma_f32_16x16x32_f16(af, bfr, acc[nt], 0, 0, 0);
        }
        __syncthreads();
    }

    // epilogue: bias + store (lane owns rows quad*4+r4 of subtile, col n16)
    #pragma unroll
    for (int nt = 0; nt < 4; nt++) {
        const int col = col0 + nt * 16 + n16;
        const float bb = bias[col];
        #pragma unroll
        for (int r4 = 0; r4 < 4; r4++) {
            const int row = row0 + wv * 16 + quad * 4 + r4;
            gx[(size_t)row * G3 + col] = acc[nt][r4] + bb;
        }
    }
}

// ---------------------------------------------------------------------------
// gru_pipeline (R22): R21 base (proven 711 us) with ONE change — hybrid
// per-step barrier:
//   OLD: slot-write arrive + pure-spin poll. Exit latency after the last
//        arrival = one full LDS poll round-trip (~120-150 cy) because the
//        pollers' in-flight reads miss the final write.
//   NEW: slot-write arrive (DS-queue ordered behind the wave's hS writes —
//        visibility token) -> bare s_barrier (fast HW wave-sync, ~50 cy;
//        all slot writes are now ISSUED) -> verify-poll that normally
//        succeeds on the FIRST read. Correctness identical (the poll still
//        proves visibility); expected wait drops by ~1-2 LDS round-trips.
// ---------------------------------------------------------------------------
__global__ __launch_bounds__(512, 2) void gru_pipeline(
    const float* __restrict__ gx0,        // [64][512][384]
    const float* __restrict__ w_ih_rest,  // [4][384][128]
    const float* __restrict__ w_hh,       // [5][384][128]
    const float* __restrict__ b_ih,       // [5][384]
    const float* __restrict__ b_hh,       // [5][384]
    _Float16* __restrict__ hmid,          // [4][4][512][16][128]
    float* __restrict__ hlast,            // [64][128]
    int* __restrict__ flags)              // [16]
{
    const int l    = blockIdx.x >> 2;
    const int g    = blockIdx.x & 3;
    const int bm0  = g * 16;
    const int tid  = threadIdx.x;
    const int lane = tid & 63;
    const int n16  = lane & 15;
    const int quad = lane >> 4;
    const int wv   = tid >> 6;
    const int j    = wv * 16 + n16;       // hidden index this lane finalizes

    __shared__ __align__(16) _Float16 hS[CHUNK][16][136];   // h ring: h(t) at hS[t&7]
    __shared__ __align__(16) int bslots[8];                 // per-wave arrival slots

    // ---- B-frags for w_hh ----
    f16x8 bf[3][4];
    {
        const float* wb = w_hh + (size_t)l * G3 * HID;
        #pragma unroll
        for (int tau = 0; tau < 3; tau++)
            #pragma unroll
            for (int kc = 0; kc < 4; kc++) {
                const float* wp = wb + (size_t)(tau * 128 + j) * HID + kc * 32 + quad * 8;
                f16x8 v;
                #pragma unroll
                for (int i = 0; i < 8; i++) v[i] = (_Float16)wp[i];
                bf[tau][kc] = v;
            }
    }
    // ---- B-frags for w_ih (layers >= 1) ----
    f16x8 bi[3][4];
    if (l > 0) {
        const float* wb = w_ih_rest + (size_t)(l - 1) * G3 * HID;
        #pragma unroll
        for (int tau = 0; tau < 3; tau++)
            #pragma unroll
            for (int kc = 0; kc < 4; kc++) {
                const float* wp = wb + (size_t)(tau * 128 + j) * HID + kc * 32 + quad * 8;
                f16x8 v;
                #pragma unroll
                for (int i = 0; i < 8; i++) v[i] = (_Float16)wp[i];
                bi[tau][kc] = v;
            }
    }
    // gate biases (gx0 already contains b_ih for layer 0); folded into acc init
    const float bcr = b_hh[l * G3 + j]       + ((l > 0) ? b_ih[l * G3 + j]       : 0.f);
    const float bcz = b_hh[l * G3 + j + 128] + ((l > 0) ? b_ih[l * G3 + j + 128] : 0.f);
    const float bcn = b_hh[l * G3 + j + 256];                      // n-gate: b_hh inside r*(...)
    const float bxn = (l > 0) ? b_ih[l * G3 + j + 256] : 0.f;      // n-gate: b_ih outside

    // ---- zero h ring (hS[7] is h(-1) = 0 for the first step) ----
    for (int i = tid; i < CHUNK * 16 * 136; i += 512) ((_Float16*)hS)[i] = (_Float16)0.f;
    float vhp[4] = {0.f, 0.f, 0.f, 0.f};
    if (tid < 8) bslots[tid] = 0;

    // ---- layer-0 gx pointers + preload t=0 ----
    const float* pR[4];
    float xr[4], xz[4], xn[4];
    if (l == 0) {
        #pragma unroll
        for (int r = 0; r < 4; r++) {
            pR[r] = gx0 + (size_t)(bm0 + quad * 4 + r) * SEQ * G3 + j;
            xr[r] = pR[r][0]; xz[r] = pR[r][128]; xn[r] = pR[r][256];
            pR[r] += G3;
        }
    }

    const _Float16* hprev = (l > 0) ? hmid + (size_t)((l - 1) * 4 + g) * SEQ * 2048 : (const _Float16*)nullptr;
    _Float16*       hpub  = (l < 4) ? hmid + (size_t)(l * 4 + g) * SEQ * 2048 : (_Float16*)nullptr;
    int*       dstflag = (l < 4) ? &flags[l * 4 + g] : (int*)nullptr;
    const int* srcflag = (l > 0) ? &flags[(l - 1) * 4 + g] : (const int*)nullptr;

    f16x8 ap[4];                             // h_prev(t) A-frags
    const int hoff = n16 * 128 + quad * 8;   // A-frag base (m=n16, k=quad*8)

    __syncthreads();   // hS zero + bslots visible

    volatile int* vb = bslots;
    const int myslot = lane & 7;

    for (int c = 0; c < SEQ / CHUNK; c++) {
        const int t0 = c * CHUNK;

        if (l > 0) {
            // once-per-chunk: relaxed spin, then ONE acquire load (buffer_inv)
            const int need = t0 + CHUNK;
            int v = __hip_atomic_load(srcflag, __ATOMIC_RELAXED, __HIP_MEMORY_SCOPE_AGENT);
            while (v < need) {
                __builtin_amdgcn_s_sleep(2);
                v = __hip_atomic_load(srcflag, __ATOMIC_RELAXED, __HIP_MEMORY_SCOPE_AGENT);
            }
            (void)__hip_atomic_load(srcflag, __ATOMIC_ACQUIRE, __HIP_MEMORY_SCOPE_AGENT);
            __asm__ volatile("" ::: "memory");
            const _Float16* hp = hprev + (size_t)t0 * 2048 + hoff;
            #pragma unroll
            for (int kc = 0; kc < 4; kc++) ap[kc] = *(const f16x8*)(hp + kc * 32);
        }

        #pragma unroll
        for (int i = 0; i < CHUNK; i++) {
            const int t = t0 + i;
            const int sc = t + 1;   // step counter for this barrier

            // ---- hybrid barrier: slot-write + s_barrier + verify-poll ----
            // arrive: plain ds_write, DS-queue ordered behind this wave's
            // previous hS writes (visibility token, no RMW).
            __asm__ volatile("" ::: "memory");
            if (lane == 0) vb[wv] = sc;
            // fast HW wave-sync: all waves have ISSUED their slot writes.
            __builtin_amdgcn_s_barrier();
            // verify visibility (normally 1 iteration: writes landed during
            // barrier arbitration).
            {
                int v;
                do { v = vb[myslot]; } while (!__all(v >= sc));
            }
            __asm__ volatile("" ::: "memory");

            // issue af LDS reads first (latency overlapped by ih MFMAs below)
            const int rb = (i + CHUNK - 1) & (CHUNK - 1);   // h(t-1) slot (compile-time per i)
            f16x8 af[4];
            #pragma unroll
            for (int kc = 0; kc < 4; kc++)
                af[kc] = *(const f16x8*)&hS[rb][n16][kc * 32 + quad * 8];

            // ih MFMAs (register inputs, no LDS dependency) — issue first.
            // bias folding: ai2 starts at bxn (n-gate b_ih, outside r*()).
            f32x4 ai0 = {0.f, 0.f, 0.f, 0.f}, ai1 = ai0;
            f32x4 ai2 = {bxn, bxn, bxn, bxn};
            if (l > 0) {
                #pragma unroll
                for (int kc = 0; kc < 4; kc++) {
                    ai0 = __builtin_amdgcn_mfma_f32_16x16x32_f16(ap[kc], bi[0][kc], ai0, 0, 0, 0);
                    ai1 = __builtin_amdgcn_mfma_f32_16x16x32_f16(ap[kc], bi[1][kc], ai1, 0, 0, 0);
                    ai2 = __builtin_amdgcn_mfma_f32_16x16x32_f16(ap[kc], bi[2][kc], ai2, 0, 0, 0);
                }
            }

            // EARLY in-chunk prefetch of h_prev(t+1): ap is dead after the ih
            // MFMAs above; hh MFMAs + finalize + barrier cover the latency.
            if (l > 0 && i < CHUNK - 1) {
                const _Float16* hp = hprev + (size_t)(t + 1) * 2048 + hoff;
                #pragma unroll
                for (int kc = 0; kc < 4; kc++) ap[kc] = *(const f16x8*)(hp + kc * 32);
            }

            // layer-0: issue gx(t+1) prefetch
            float nr[4], nz[4], nn[4];
            if (l == 0) {
                #pragma unroll
                for (int r = 0; r < 4; r++) {
                    nr[r] = pR[r][0]; nz[r] = pR[r][128]; nn[r] = pR[r][256];
                }
                if (t + 1 < SEQ) {
                    #pragma unroll
                    for (int r = 0; r < 4; r++) pR[r] += G3;
                }
            }

            // hh MFMAs — biases folded into C-init (bcr, bcz, bcn)
            f32x4 ah0 = {bcr, bcr, bcr, bcr};
            f32x4 ah1 = {bcz, bcz, bcz, bcz};
            f32x4 ah2 = {bcn, bcn, bcn, bcn};
            #pragma unroll
            for (int kc = 0; kc < 4; kc++) {
                ah0 = __builtin_amdgcn_mfma_f32_16x16x32_f16(af[kc], bf[0][kc], ah0, 0, 0, 0);
                ah1 = __builtin_amdgcn_mfma_f32_16x16x32_f16(af[kc], bf[1][kc], ah1, 0, 0, 0);
                ah2 = __builtin_amdgcn_mfma_f32_16x16x32_f16(af[kc], bf[2][kc], ah2, 0, 0, 0);
            }

            // finalize: lane owns (m = quad*4+r, j) for all gates
            #pragma unroll
            for (int r = 0; r < 4; r++) {
                const float sxr = (l == 0) ? xr[r] : ai0[r];
                const float sxz = (l == 0) ? xz[r] : ai1[r];
                const float sxn = (l == 0) ? xn[r] : ai2[r];
                const float rg  = sigf(sxr + ah0[r]);
                const float zg  = sigf(sxz + ah1[r]);
                const float th  = tanh_fast(fmaf(rg, ah2[r], sxn));
                const float hnew = fmaf(zg, vhp[r] - th, th);   // (1-z)n + z h
                vhp[r] = hnew;
                hS[i][quad * 4 + r][j] = (_Float16)hnew;        // single h write (ring)
                if (l == 4 && t == SEQ - 1)
                    hlast[(bm0 + quad * 4 + r) * 128 + j] = hnew;
            }

            if (l == 0) {
                #pragma unroll
                for (int r = 0; r < 4; r++) { xr[r] = nr[r]; xz[r] = nz[r]; xn[r] = nn[r]; }
            }
        }

        // ---- chunk boundary (producers only): flush ring -> hmid, RELEASE.
        // l==4 skips entirely: no flush/release; the per-step flag barrier
        // alone protects hS ring reuse (slot rewritten 8 barriers after its
        // last read).
        if (l < 4) {
            __syncthreads();                   // all waves' hS writes visible
            _Float16* dstc = hpub + (size_t)t0 * 2048;
            {
                const int seg0 = tid;            // 0..511
                const int seg1 = tid + 512;
                const int seg2 = tid + 1024;
                const int seg3 = tid + 1536;
                f16x8 v0 = *(const f16x8*)&hS[(seg0 >> 8)][(seg0 >> 4) & 15][(seg0 & 15) * 8];
                f16x8 v1 = *(const f16x8*)&hS[(seg1 >> 8)][(seg1 >> 4) & 15][(seg1 & 15) * 8];
                f16x8 v2 = *(const f16x8*)&hS[(seg2 >> 8)][(seg2 >> 4) & 15][(seg2 & 15) * 8];
                f16x8 v3 = *(const f16x8*)&hS[(seg3 >> 8)][(seg3 >> 4) & 15][(seg3 & 15) * 8];
                *(f16x8*)(dstc + (seg0 >> 4) * 128 + (seg0 & 15) * 8) = v0;
                *(f16x8*)(dstc + (seg1 >> 4) * 128 + (seg1 & 15) * 8) = v1;
                *(f16x8*)(dstc + (seg2 >> 4) * 128 + (seg2 & 15) * 8) = v2;
                *(f16x8*)(dstc + (seg3 >> 4) * 128 + (seg3 & 15) * 8) = v3;
            }
            __syncthreads();                   // drains vmcnt (stores retired)
            if (tid == 0)
                __hip_atomic_store(dstflag, t0 + CHUNK, __ATOMIC_RELEASE, __HIP_MEMORY_SCOPE_AGENT);
        }
    }
}

// ---------------------------------------------------------------------------
// fc: out[b][o] = hlast[b][:] . fc_w[o][:] + fc_b[o]
// ---------------------------------------------------------------------------
__global__ __launch_bounds__(128) void fc_kernel(const float* __restrict__ hlast,
                                                 const float* __restrict__ fc_w,
                                                 const float* __restrict__ fc_b,
                                                 float* __restrict__ out)
{
    const int b = blockIdx.x;
    const int o = threadIdx.x;
    if (o < 96) {
        const float* h = hlast + (size_t)b * HID;
        const float* wrow = fc_w + o * HID;
        float acc = fc_b[o];
        #pragma unroll 4
        for (int k = 0; k < HID; k++) acc = fmaf(h[k], wrow[k], acc);
        out[b * 96 + o] = acc;
    }
}

// ---------------------------------------------------------------------------
extern "C" void kernel_launch(void* const* d_in, const int* in_sizes, int n_in,
                              void* d_out, int out_size, void* d_ws, size_t ws_size,
                              hipStream_t stream)
{
    const float* x         = (const float*)d_in[0]; // [64][512][512]
    const float* w_ih0     = (const float*)d_in[1]; // [384][512]
    const float* w_ih_rest = (const float*)d_in[2]; // [4][384][128]
    const float* w_hh      = (const float*)d_in[3]; // [5][384][128]
    const float* b_ih      = (const float*)d_in[4]; // [5][384]
    const float* b_hh      = (const float*)d_in[5]; // [5][384]
    const float* fc_w      = (const float*)d_in[6]; // [96][128]
    const float* fc_b      = (const float*)d_in[7]; // [96]
    float* out = (float*)d_out;                     // [64][96]

    // workspace layout:
    //   [0,256)              flags (16 ints, zeroed each launch)
    //   [256, +50331648)     gxbuf fp32 [64][512][384]
    //   [.., +33554432)      hmid  f16  [4][4][512][16][128]
    //   [.., +32768)         hlast fp32 [64][128]
    int*      flags = (int*)d_ws;
    float*    gxbuf = (float*)((char*)d_ws + 256);
    _Float16* hmid  = (_Float16*)((char*)d_ws + 256 + 50331648);
    float*    hlast = (float*)((char*)d_ws + 256 + 50331648 + 33554432);

    hipMemsetAsync(d_ws, 0, 256, stream);

    const dim3 gemmGrid(512, 6);
    gemm_gx<<<gemmGrid, 256, 0, stream>>>(x, w_ih0, b_ih, gxbuf);

    gru_pipeline<<<NLAY * 4, 512, 0, stream>>>(gxbuf, w_ih_rest, w_hh, b_ih, b_hh,
                                               hmid, hlast, flags);

    fc_kernel<<<BATCH, 128, 0, stream>>>(hlast, fc_w, fc_b, out);
}

// Round 14
// 923.415 us; speedup vs baseline: 1.1339x; 1.1339x over previous
//
#include <hip/hip_runtime.h>
#include <hip/hip_bf16.h>

// Problem constants
#define BATCH   64
#define SEQ     512
#define IN0     512
#define HID     128
#define G3      384   // 3*HID
#define NLAY    5
#define CHUNK   8     // handoff granularity (one release/acquire per CHUNK steps)

typedef _Float16 f16x8 __attribute__((ext_vector_type(8)));
typedef float    f32x4 __attribute__((ext_vector_type(4)));

static __device__ __forceinline__ float sigf(float x) {
    return __builtin_amdgcn_rcpf(1.f + __expf(-x));
}
static __device__ __forceinline__ float tanh_fast(float x) {
    // exp(-2|x|) = exp2(|x| * -2*log2(e)); single mul + v_exp
    const float e = exp2f(fabsf(x) * -2.885390082f);
    return copysignf((1.f - e) * __builtin_amdgcn_rcpf(1.f + e), x);
}

// ---------------------------------------------------------------------------
// gru_fused (R23): ONE kernel = 20 gru blocks (R21-verbatim internals:
// slot barrier + pure spin; R22's s_barrier hybrid REVERTED — both s_barrier
// variants (R12, R22) cost ~180us via compiler-inserted waitcnt drains) +
// 3072 gemm blocks computing gx0 CONCURRENTLY, t-major ordered.
// Producer/consumer: gemm block (64 rows = one (b, 64-t window) x 64 cols)
// finishes -> __syncthreads (drains own stores) -> tid0 fetch_add(RELEASE)
// on gxdone[g][window] (96 blocks/window). gru layer-0 acquires each window
// before reading it (once per 8 chunks). Removes the ~140us serial gemm.
// No deadlock: 20 spinning gru blocks can't fill 256 CUs.
// ---------------------------------------------------------------------------
__global__ __launch_bounds__(512, 2) void gru_fused(
    const float* __restrict__ x,          // [64][512][512]
    const float* __restrict__ w_ih0,      // [384][512]
    float* __restrict__ gx,               // gxbuf [32768][384]
    const float* __restrict__ w_ih_rest,  // [4][384][128]
    const float* __restrict__ w_hh,       // [5][384][128]
    const float* __restrict__ b_ih,       // [5][384]
    const float* __restrict__ b_hh,       // [5][384]
    _Float16* __restrict__ hmid,          // [4][4][512][16][128]
    float* __restrict__ hlast,            // [64][128]
    int* __restrict__ flags)              // [0..15] layer handoff, [16..47] gxdone
{
    __shared__ __align__(16) char smem[34848];   // union: gru 34848 B / gemm 10240 B

    const int tid  = threadIdx.x;
    const int lane = tid & 63;
    const int n16  = lane & 15;
    const int quad = lane >> 4;

    if (blockIdx.x >= 20) {
        // ================= gemm role =================
        const int gi    = blockIdx.x - 20;
        const int tslot = gi / 384;          // 0..7  (64-step t window) — t-major
        const int rem   = gi % 384;
        const int bb    = rem / 6;           // batch 0..63
        const int nb    = rem % 6;           // col block 0..5
        const int row0  = bb * 512 + tslot * 64;
        const int col0  = nb * 64;

        _Float16 (*As)[40] = (_Float16(*)[40])smem;            // [64][40]
        _Float16 (*Bs)[40] = (_Float16(*)[40])(smem + 5120);   // [64][40]

        const int wv   = tid >> 6;
        const int msub = wv & 3;             // m-subtile 0..3 (16 rows)
        const int nh   = wv >> 2;            // n-half 0..1 (32 cols)

        f32x4 acc0 = {0.f, 0.f, 0.f, 0.f}, acc1 = acc0;

        // staging: threads 0..255 stage A (x), 256..511 stage B (w_ih0)
        const int half = tid >> 8;
        const int u    = tid & 255;
        const int r    = u >> 2;             // 0..63
        const int kc   = (u & 3) * 8;        // 0,8,16,24
        const float* src0 = (half == 0)
            ? x     + (size_t)(row0 + r) * IN0
            : w_ih0 + (size_t)(col0 + r) * IN0;
        _Float16* dst = (half == 0) ? &As[r][kc] : &Bs[r][kc];

        for (int k0 = 0; k0 < IN0; k0 += 32) {
            float4 a0 = *(const float4*)(src0 + k0 + kc);
            float4 a1 = *(const float4*)(src0 + k0 + kc + 4);
            f16x8 v;
            v[0] = (_Float16)a0.x; v[1] = (_Float16)a0.y; v[2] = (_Float16)a0.z; v[3] = (_Float16)a0.w;
            v[4] = (_Float16)a1.x; v[5] = (_Float16)a1.y; v[6] = (_Float16)a1.z; v[7] = (_Float16)a1.w;
            *(f16x8*)dst = v;
            __syncthreads();
            const f16x8 af  = *(const f16x8*)&As[msub * 16 + n16][quad * 8];
            const f16x8 bf0 = *(const f16x8*)&Bs[nh * 32 + n16][quad * 8];
            const f16x8 bf1 = *(const f16x8*)&Bs[nh * 32 + 16 + n16][quad * 8];
            acc0 = __builtin_amdgcn_mfma_f32_16x16x32_f16(af, bf0, acc0, 0, 0, 0);
            acc1 = __builtin_amdgcn_mfma_f32_16x16x32_f16(af, bf1, acc1, 0, 0, 0);
            __syncthreads();
        }
        // epilogue: bias (layer-0 b_ih) + store
        #pragma unroll
        for (int nt = 0; nt < 2; nt++) {
            const f32x4 a = nt ? acc1 : acc0;
            const int col = col0 + nh * 32 + nt * 16 + n16;
            const float bbias = b_ih[col];
            #pragma unroll
            for (int r4 = 0; r4 < 4; r4++) {
                const int row = row0 + msub * 16 + quad * 4 + r4;
                gx[(size_t)row * G3 + col] = a[r4] + bbias;
            }
        }
        __syncthreads();   // each wave drains its own vmcnt (stores retired)
        if (tid == 0)
            __hip_atomic_fetch_add(&flags[16 + (bb >> 4) * 8 + tslot], 1,
                                   __ATOMIC_RELEASE, __HIP_MEMORY_SCOPE_AGENT);
        return;
    }

    // ================= gru role (R21 internals) =================
    const int l    = blockIdx.x >> 2;
    const int g    = blockIdx.x & 3;
    const int bm0  = g * 16;
    const int wv   = tid >> 6;
    const int j    = wv * 16 + n16;       // hidden index this lane finalizes

    _Float16 (*hS)[16][136] = (_Float16(*)[16][136])smem;   // [8][16][136] ring
    int* bslots = (int*)(smem + 34816);                     // per-wave arrival slots

    // ---- B-frags for w_hh ----
    f16x8 bf[3][4];
    {
        const float* wb = w_hh + (size_t)l * G3 * HID;
        #pragma unroll
        for (int tau = 0; tau < 3; tau++)
            #pragma unroll
            for (int kc = 0; kc < 4; kc++) {
                const float* wp = wb + (size_t)(tau * 128 + j) * HID + kc * 32 + quad * 8;
                f16x8 v;
                #pragma unroll
                for (int i = 0; i < 8; i++) v[i] = (_Float16)wp[i];
                bf[tau][kc] = v;
            }
    }
    // ---- B-frags for w_ih (layers >= 1) ----
    f16x8 bi[3][4];
    if (l > 0) {
        const float* wb = w_ih_rest + (size_t)(l - 1) * G3 * HID;
        #pragma unroll
        for (int tau = 0; tau < 3; tau++)
            #pragma unroll
            for (int kc = 0; kc < 4; kc++) {
                const float* wp = wb + (size_t)(tau * 128 + j) * HID + kc * 32 + quad * 8;
                f16x8 v;
                #pragma unroll
                for (int i = 0; i < 8; i++) v[i] = (_Float16)wp[i];
                bi[tau][kc] = v;
            }
    }
    // gate biases (gx already contains layer-0 b_ih); folded into acc init
    const float bcr = b_hh[l * G3 + j]       + ((l > 0) ? b_ih[l * G3 + j]       : 0.f);
    const float bcz = b_hh[l * G3 + j + 128] + ((l > 0) ? b_ih[l * G3 + j + 128] : 0.f);
    const float bcn = b_hh[l * G3 + j + 256];                      // n-gate: b_hh inside r*(...)
    const float bxn = (l > 0) ? b_ih[l * G3 + j + 256] : 0.f;      // n-gate: b_ih outside

    // ---- zero h ring ----
    for (int i = tid; i < CHUNK * 16 * 136; i += 512) ((_Float16*)hS)[i] = (_Float16)0.f;
    float vhp[4] = {0.f, 0.f, 0.f, 0.f};
    if (tid < 8) bslots[tid] = 0;

    // ---- layer-0: wait gx window 0 (gemm producers), then preload t=0 ----
    const float* pR[4];
    float xr[4], xz[4], xn[4];
    const int* gxw = &flags[16 + g * 8];
    if (l == 0) {
        int v = __hip_atomic_load(&gxw[0], __ATOMIC_RELAXED, __HIP_MEMORY_SCOPE_AGENT);
        while (v < 96) {
            __builtin_amdgcn_s_sleep(2);
            v = __hip_atomic_load(&gxw[0], __ATOMIC_RELAXED, __HIP_MEMORY_SCOPE_AGENT);
        }
        (void)__hip_atomic_load(&gxw[0], __ATOMIC_ACQUIRE, __HIP_MEMORY_SCOPE_AGENT);
        __asm__ volatile("" ::: "memory");
        #pragma unroll
        for (int r = 0; r < 4; r++) {
            pR[r] = gx + (size_t)(bm0 + quad * 4 + r) * SEQ * G3 + j;
            xr[r] = pR[r][0]; xz[r] = pR[r][128]; xn[r] = pR[r][256];
            pR[r] += G3;
        }
    }
    int wcur = 0;

    const _Float16* hprev = (l > 0) ? hmid + (size_t)((l - 1) * 4 + g) * SEQ * 2048 : (const _Float16*)nullptr;
    _Float16*       hpub  = (l < 4) ? hmid + (size_t)(l * 4 + g) * SEQ * 2048 : (_Float16*)nullptr;
    int*       dstflag = (l < 4) ? &flags[l * 4 + g] : (int*)nullptr;
    const int* srcflag = (l > 0) ? &flags[(l - 1) * 4 + g] : (const int*)nullptr;

    f16x8 ap[4];                             // h_prev(t) A-frags
    const int hoff = n16 * 128 + quad * 8;   // A-frag base (m=n16, k=quad*8)

    __syncthreads();   // hS zero + bslots visible

    volatile int* vb = bslots;
    const int myslot = lane & 7;

    for (int c = 0; c < SEQ / CHUNK; c++) {
        const int t0 = c * CHUNK;

        if (l > 0) {
            // once-per-chunk: relaxed spin, then ONE acquire load (buffer_inv)
            const int need = t0 + CHUNK;
            int v = __hip_atomic_load(srcflag, __ATOMIC_RELAXED, __HIP_MEMORY_SCOPE_AGENT);
            while (v < need) {
                __builtin_amdgcn_s_sleep(2);
                v = __hip_atomic_load(srcflag, __ATOMIC_RELAXED, __HIP_MEMORY_SCOPE_AGENT);
            }
            (void)__hip_atomic_load(srcflag, __ATOMIC_ACQUIRE, __HIP_MEMORY_SCOPE_AGENT);
            __asm__ volatile("" ::: "memory");
            const _Float16* hp = hprev + (size_t)t0 * 2048 + hoff;
            #pragma unroll
            for (int kc = 0; kc < 4; kc++) ap[kc] = *(const f16x8*)(hp + kc * 32);
        } else {
            // layer-0: gate on gx window containing reads up to t0+CHUNK
            int wneed = (t0 + CHUNK) >> 6; if (wneed > 7) wneed = 7;
            if (wneed != wcur) {
                int v = __hip_atomic_load(&gxw[wneed], __ATOMIC_RELAXED, __HIP_MEMORY_SCOPE_AGENT);
                while (v < 96) {
                    __builtin_amdgcn_s_sleep(2);
                    v = __hip_atomic_load(&gxw[wneed], __ATOMIC_RELAXED, __HIP_MEMORY_SCOPE_AGENT);
                }
                (void)__hip_atomic_load(&gxw[wneed], __ATOMIC_ACQUIRE, __HIP_MEMORY_SCOPE_AGENT);
                __asm__ volatile("" ::: "memory");
                wcur = wneed;
            }
        }

        #pragma unroll
        for (int i = 0; i < CHUNK; i++) {
            const int t = t0 + i;
            const int sc = t + 1;   // step counter for this barrier

            // ---- distributed-slot flag barrier: no vmcnt drain, pure spin ----
            __asm__ volatile("" ::: "memory");
            if (lane == 0) vb[wv] = sc;
            {
                int v;
                do { v = vb[myslot]; } while (!__all(v >= sc));
            }
            __asm__ volatile("" ::: "memory");

            // issue af LDS reads first (latency overlapped by ih MFMAs below)
            const int rb = (i + CHUNK - 1) & (CHUNK - 1);   // h(t-1) slot
            f16x8 af[4];
            #pragma unroll
            for (int kc = 0; kc < 4; kc++)
                af[kc] = *(const f16x8*)&hS[rb][n16][kc * 32 + quad * 8];

            // ih MFMAs (register inputs, no LDS dependency) — issue first.
            f32x4 ai0 = {0.f, 0.f, 0.f, 0.f}, ai1 = ai0;
            f32x4 ai2 = {bxn, bxn, bxn, bxn};
            if (l > 0) {
                #pragma unroll
                for (int kc = 0; kc < 4; kc++) {
                    ai0 = __builtin_amdgcn_mfma_f32_16x16x32_f16(ap[kc], bi[0][kc], ai0, 0, 0, 0);
                    ai1 = __builtin_amdgcn_mfma_f32_16x16x32_f16(ap[kc], bi[1][kc], ai1, 0, 0, 0);
                    ai2 = __builtin_amdgcn_mfma_f32_16x16x32_f16(ap[kc], bi[2][kc], ai2, 0, 0, 0);
                }
            }

            // EARLY in-chunk prefetch of h_prev(t+1)
            if (l > 0 && i < CHUNK - 1) {
                const _Float16* hp = hprev + (size_t)(t + 1) * 2048 + hoff;
                #pragma unroll
                for (int kc = 0; kc < 4; kc++) ap[kc] = *(const f16x8*)(hp + kc * 32);
            }

            // layer-0: issue gx(t+1) prefetch
            float nr[4], nz[4], nn[4];
            if (l == 0) {
                #pragma unroll
                for (int r = 0; r < 4; r++) {
                    nr[r] = pR[r][0]; nz[r] = pR[r][128]; nn[r] = pR[r][256];
                }
                if (t + 1 < SEQ) {
                    #pragma unroll
                    for (int r = 0; r < 4; r++) pR[r] += G3;
                }
            }

            // hh MFMAs — biases folded into C-init (bcr, bcz, bcn)
            f32x4 ah0 = {bcr, bcr, bcr, bcr};
            f32x4 ah1 = {bcz, bcz, bcz, bcz};
            f32x4 ah2 = {bcn, bcn, bcn, bcn};
            #pragma unroll
            for (int kc = 0; kc < 4; kc++) {
                ah0 = __builtin_amdgcn_mfma_f32_16x16x32_f16(af[kc], bf[0][kc], ah0, 0, 0, 0);
                ah1 = __builtin_amdgcn_mfma_f32_16x16x32_f16(af[kc], bf[1][kc], ah1, 0, 0, 0);
                ah2 = __builtin_amdgcn_mfma_f32_16x16x32_f16(af[kc], bf[2][kc], ah2, 0, 0, 0);
            }

            // finalize: lane owns (m = quad*4+r, j) for all gates
            #pragma unroll
            for (int r = 0; r < 4; r++) {
                const float sxr = (l == 0) ? xr[r] : ai0[r];
                const float sxz = (l == 0) ? xz[r] : ai1[r];
                const float sxn = (l == 0) ? xn[r] : ai2[r];
                const float rg  = sigf(sxr + ah0[r]);
                const float zg  = sigf(sxz + ah1[r]);
                const float th  = tanh_fast(fmaf(rg, ah2[r], sxn));
                const float hnew = fmaf(zg, vhp[r] - th, th);   // (1-z)n + z h
                vhp[r] = hnew;
                hS[i][quad * 4 + r][j] = (_Float16)hnew;        // single h write (ring)
                if (l == 4 && t == SEQ - 1)
                    hlast[(bm0 + quad * 4 + r) * 128 + j] = hnew;
            }

            if (l == 0) {
                #pragma unroll
                for (int r = 0; r < 4; r++) { xr[r] = nr[r]; xz[r] = nz[r]; xn[r] = nn[r]; }
            }
        }

        // ---- chunk boundary (producers only): flush ring -> hmid, RELEASE.
        // l==4 skips entirely (per-step barrier protects ring reuse).
        if (l < 4) {
            __syncthreads();                   // all waves' hS writes visible
            _Float16* dstc = hpub + (size_t)t0 * 2048;
            {
                const int seg0 = tid;            // 0..511
                const int seg1 = tid + 512;
                const int seg2 = tid + 1024;
                const int seg3 = tid + 1536;
                f16x8 v0 = *(const f16x8*)&hS[(seg0 >> 8)][(seg0 >> 4) & 15][(seg0 & 15) * 8];
                f16x8 v1 = *(const f16x8*)&hS[(seg1 >> 8)][(seg1 >> 4) & 15][(seg1 & 15) * 8];
                f16x8 v2 = *(const f16x8*)&hS[(seg2 >> 8)][(seg2 >> 4) & 15][(seg2 & 15) * 8];
                f16x8 v3 = *(const f16x8*)&hS[(seg3 >> 8)][(seg3 >> 4) & 15][(seg3 & 15) * 8];
                *(f16x8*)(dstc + (seg0 >> 4) * 128 + (seg0 & 15) * 8) = v0;
                *(f16x8*)(dstc + (seg1 >> 4) * 128 + (seg1 & 15) * 8) = v1;
                *(f16x8*)(dstc + (seg2 >> 4) * 128 + (seg2 & 15) * 8) = v2;
                *(f16x8*)(dstc + (seg3 >> 4) * 128 + (seg3 & 15) * 8) = v3;
            }
            __syncthreads();                   // drains vmcnt (stores retired)
            if (tid == 0)
                __hip_atomic_store(dstflag, t0 + CHUNK, __ATOMIC_RELEASE, __HIP_MEMORY_SCOPE_AGENT);
        }
    }
}

// ---------------------------------------------------------------------------
// fc: out[b][o] = hlast[b][:] . fc_w[o][:] + fc_b[o]
// ---------------------------------------------------------------------------
__global__ __launch_bounds__(128) void fc_kernel(const float* __restrict__ hlast,
                                                 const float* __restrict__ fc_w,
                                                 const float* __restrict__ fc_b,
                                                 float* __restrict__ out)
{
    const int b = blockIdx.x;
    const int o = threadIdx.x;
    if (o < 96) {
        const float* h = hlast + (size_t)b * HID;
        const float* wrow = fc_w + o * HID;
        float acc = fc_b[o];
        #pragma unroll 4
        for (int k = 0; k < HID; k++) acc = fmaf(h[k], wrow[k], acc);
        out[b * 96 + o] = acc;
    }
}

// ---------------------------------------------------------------------------
extern "C" void kernel_launch(void* const* d_in, const int* in_sizes, int n_in,
                              void* d_out, int out_size, void* d_ws, size_t ws_size,
                              hipStream_t stream)
{
    const float* x         = (const float*)d_in[0]; // [64][512][512]
    const float* w_ih0     = (const float*)d_in[1]; // [384][512]
    const float* w_ih_rest = (const float*)d_in[2]; // [4][384][128]
    const float* w_hh      = (const float*)d_in[3]; // [5][384][128]
    const float* b_ih      = (const float*)d_in[4]; // [5][384]
    const float* b_hh      = (const float*)d_in[5]; // [5][384]
    const float* fc_w      = (const float*)d_in[6]; // [96][128]
    const float* fc_b      = (const float*)d_in[7]; // [96]
    float* out = (float*)d_out;                     // [64][96]

    // workspace layout:
    //   [0,256)              flags (64 ints: [0..15] layer handoff, [16..47] gxdone)
    //   [256, +50331648)     gxbuf fp32 [64][512][384]
    //   [.., +33554432)      hmid  f16  [4][4][512][16][128]
    //   [.., +32768)         hlast fp32 [64][128]
    int*      flags = (int*)d_ws;
    float*    gxbuf = (float*)((char*)d_ws + 256);
    _Float16* hmid  = (_Float16*)((char*)d_ws + 256 + 50331648);
    float*    hlast = (float*)((char*)d_ws + 256 + 50331648 + 33554432);

    hipMemsetAsync(d_ws, 0, 256, stream);

    // ONE launch: blocks 0..19 = gru pipeline (5 layers x 4 batch groups),
    // blocks 20..3091 = gemm producers (t-major: tslot outer, 384 per window)
    gru_fused<<<20 + 3072, 512, 0, stream>>>(x, w_ih0, gxbuf, w_ih_rest, w_hh,
                                             b_ih, b_hh, hmid, hlast, flags);

    fc_kernel<<<BATCH, 128, 0, stream>>>(hlast, fc_w, fc_b, out);
}

// Round 15
// 909.522 us; speedup vs baseline: 1.1512x; 1.0153x over previous
//
#include <hip/hip_runtime.h>
#include <hip/hip_bf16.h>

// Problem constants
#define BATCH   64
#define SEQ     512
#define IN0     512
#define HID     128
#define G3      384   // 3*HID
#define NLAY    5
#define CHUNK   8     // handoff granularity (one release/acquire per CHUNK steps)

typedef _Float16 f16x8 __attribute__((ext_vector_type(8)));
typedef float    f32x4 __attribute__((ext_vector_type(4)));

static __device__ __forceinline__ float sigf(float x) {
    return __builtin_amdgcn_rcpf(1.f + __expf(-x));
}
static __device__ __forceinline__ float tanh_fast(float x) {
    // exp(-2|x|) = exp2(|x| * -2*log2(e)); single mul + v_exp
    const float e = exp2f(fabsf(x) * -2.885390082f);
    return copysignf((1.f - e) * __builtin_amdgcn_rcpf(1.f + e), x);
}

// ---------------------------------------------------------------------------
// gru_fused (R24): R23 fused producer/consumer structure, but the shared-mem
// union is padded to 88 KB (> 160KB/2) so LDS caps occupancy at 1 block/CU:
// the 20 gru blocks own their CUs EXCLUSIVELY (R23's +117us gru-path
// inflation came from gemm blocks co-resident on gru CUs stealing issue
// slots). Gemm blocks pack 1/CU on the other ~236 CUs — gemm throughput
// halves but remains far below the gru runtime; window-0 (384 blocks)
// completes in ~2 rounds so layer-0 starts almost immediately.
// gru internals = R21 verbatim (slot barrier + pure spin).
// ---------------------------------------------------------------------------
__global__ __launch_bounds__(512, 2) void gru_fused(
    const float* __restrict__ x,          // [64][512][512]
    const float* __restrict__ w_ih0,      // [384][512]
    float* __restrict__ gx,               // gxbuf [32768][384]
    const float* __restrict__ w_ih_rest,  // [4][384][128]
    const float* __restrict__ w_hh,       // [5][384][128]
    const float* __restrict__ b_ih,       // [5][384]
    const float* __restrict__ b_hh,       // [5][384]
    _Float16* __restrict__ hmid,          // [4][4][512][16][128]
    float* __restrict__ hlast,            // [64][128]
    int* __restrict__ flags)              // [0..15] layer handoff, [16..47] gxdone
{
    __shared__ __align__(16) char smem[90112];   // 88 KB: forces 1 block/CU

    const int tid  = threadIdx.x;
    const int lane = tid & 63;
    const int n16  = lane & 15;
    const int quad = lane >> 4;

    if (blockIdx.x >= 20) {
        // ================= gemm role =================
        const int gi    = blockIdx.x - 20;
        const int tslot = gi / 384;          // 0..7  (64-step t window) — t-major
        const int rem   = gi % 384;
        const int bb    = rem / 6;           // batch 0..63
        const int nb    = rem % 6;           // col block 0..5
        const int row0  = bb * 512 + tslot * 64;
        const int col0  = nb * 64;

        _Float16 (*As)[40] = (_Float16(*)[40])smem;            // [64][40]
        _Float16 (*Bs)[40] = (_Float16(*)[40])(smem + 5120);   // [64][40]

        const int wv   = tid >> 6;
        const int msub = wv & 3;             // m-subtile 0..3 (16 rows)
        const int nh   = wv >> 2;            // n-half 0..1 (32 cols)

        f32x4 acc0 = {0.f, 0.f, 0.f, 0.f}, acc1 = acc0;

        // staging: threads 0..255 stage A (x), 256..511 stage B (w_ih0)
        const int half = tid >> 8;
        const int u    = tid & 255;
        const int r    = u >> 2;             // 0..63
        const int kc   = (u & 3) * 8;        // 0,8,16,24
        const float* src0 = (half == 0)
            ? x     + (size_t)(row0 + r) * IN0
            : w_ih0 + (size_t)(col0 + r) * IN0;
        _Float16* dst = (half == 0) ? &As[r][kc] : &Bs[r][kc];

        for (int k0 = 0; k0 < IN0; k0 += 32) {
            float4 a0 = *(const float4*)(src0 + k0 + kc);
            float4 a1 = *(const float4*)(src0 + k0 + kc + 4);
            f16x8 v;
            v[0] = (_Float16)a0.x; v[1] = (_Float16)a0.y; v[2] = (_Float16)a0.z; v[3] = (_Float16)a0.w;
            v[4] = (_Float16)a1.x; v[5] = (_Float16)a1.y; v[6] = (_Float16)a1.z; v[7] = (_Float16)a1.w;
            *(f16x8*)dst = v;
            __syncthreads();
            const f16x8 af  = *(const f16x8*)&As[msub * 16 + n16][quad * 8];
            const f16x8 bf0 = *(const f16x8*)&Bs[nh * 32 + n16][quad * 8];
            const f16x8 bf1 = *(const f16x8*)&Bs[nh * 32 + 16 + n16][quad * 8];
            acc0 = __builtin_amdgcn_mfma_f32_16x16x32_f16(af, bf0, acc0, 0, 0, 0);
            acc1 = __builtin_amdgcn_mfma_f32_16x16x32_f16(af, bf1, acc1, 0, 0, 0);
            __syncthreads();
        }
        // epilogue: bias (layer-0 b_ih) + store
        #pragma unroll
        for (int nt = 0; nt < 2; nt++) {
            const f32x4 a = nt ? acc1 : acc0;
            const int col = col0 + nh * 32 + nt * 16 + n16;
            const float bbias = b_ih[col];
            #pragma unroll
            for (int r4 = 0; r4 < 4; r4++) {
                const int row = row0 + msub * 16 + quad * 4 + r4;
                gx[(size_t)row * G3 + col] = a[r4] + bbias;
            }
        }
        __syncthreads();   // each wave drains its own vmcnt (stores retired)
        if (tid == 0)
            __hip_atomic_fetch_add(&flags[16 + (bb >> 4) * 8 + tslot], 1,
                                   __ATOMIC_RELEASE, __HIP_MEMORY_SCOPE_AGENT);
        return;
    }

    // ================= gru role (R21 internals) =================
    const int l    = blockIdx.x >> 2;
    const int g    = blockIdx.x & 3;
    const int bm0  = g * 16;
    const int wv   = tid >> 6;
    const int j    = wv * 16 + n16;       // hidden index this lane finalizes

    _Float16 (*hS)[16][136] = (_Float16(*)[16][136])smem;   // [8][16][136] ring
    int* bslots = (int*)(smem + 34816);                     // per-wave arrival slots

    // ---- B-frags for w_hh ----
    f16x8 bf[3][4];
    {
        const float* wb = w_hh + (size_t)l * G3 * HID;
        #pragma unroll
        for (int tau = 0; tau < 3; tau++)
            #pragma unroll
            for (int kc = 0; kc < 4; kc++) {
                const float* wp = wb + (size_t)(tau * 128 + j) * HID + kc * 32 + quad * 8;
                f16x8 v;
                #pragma unroll
                for (int i = 0; i < 8; i++) v[i] = (_Float16)wp[i];
                bf[tau][kc] = v;
            }
    }
    // ---- B-frags for w_ih (layers >= 1) ----
    f16x8 bi[3][4];
    if (l > 0) {
        const float* wb = w_ih_rest + (size_t)(l - 1) * G3 * HID;
        #pragma unroll
        for (int tau = 0; tau < 3; tau++)
            #pragma unroll
            for (int kc = 0; kc < 4; kc++) {
                const float* wp = wb + (size_t)(tau * 128 + j) * HID + kc * 32 + quad * 8;
                f16x8 v;
                #pragma unroll
                for (int i = 0; i < 8; i++) v[i] = (_Float16)wp[i];
                bi[tau][kc] = v;
            }
    }
    // gate biases (gx already contains layer-0 b_ih); folded into acc init
    const float bcr = b_hh[l * G3 + j]       + ((l > 0) ? b_ih[l * G3 + j]       : 0.f);
    const float bcz = b_hh[l * G3 + j + 128] + ((l > 0) ? b_ih[l * G3 + j + 128] : 0.f);
    const float bcn = b_hh[l * G3 + j + 256];                      // n-gate: b_hh inside r*(...)
    const float bxn = (l > 0) ? b_ih[l * G3 + j + 256] : 0.f;      // n-gate: b_ih outside

    // ---- zero h ring ----
    for (int i = tid; i < CHUNK * 16 * 136; i += 512) ((_Float16*)hS)[i] = (_Float16)0.f;
    float vhp[4] = {0.f, 0.f, 0.f, 0.f};
    if (tid < 8) bslots[tid] = 0;

    // ---- layer-0: wait gx window 0 (gemm producers), then preload t=0 ----
    const float* pR[4];
    float xr[4], xz[4], xn[4];
    const int* gxw = &flags[16 + g * 8];
    if (l == 0) {
        int v = __hip_atomic_load(&gxw[0], __ATOMIC_RELAXED, __HIP_MEMORY_SCOPE_AGENT);
        while (v < 96) {
            __builtin_amdgcn_s_sleep(2);
            v = __hip_atomic_load(&gxw[0], __ATOMIC_RELAXED, __HIP_MEMORY_SCOPE_AGENT);
        }
        (void)__hip_atomic_load(&gxw[0], __ATOMIC_ACQUIRE, __HIP_MEMORY_SCOPE_AGENT);
        __asm__ volatile("" ::: "memory");
        #pragma unroll
        for (int r = 0; r < 4; r++) {
            pR[r] = gx + (size_t)(bm0 + quad * 4 + r) * SEQ * G3 + j;
            xr[r] = pR[r][0]; xz[r] = pR[r][128]; xn[r] = pR[r][256];
            pR[r] += G3;
        }
    }
    int wcur = 0;

    const _Float16* hprev = (l > 0) ? hmid + (size_t)((l - 1) * 4 + g) * SEQ * 2048 : (const _Float16*)nullptr;
    _Float16*       hpub  = (l < 4) ? hmid + (size_t)(l * 4 + g) * SEQ * 2048 : (_Float16*)nullptr;
    int*       dstflag = (l < 4) ? &flags[l * 4 + g] : (int*)nullptr;
    const int* srcflag = (l > 0) ? &flags[(l - 1) * 4 + g] : (const int*)nullptr;

    f16x8 ap[4];                             // h_prev(t) A-frags
    const int hoff = n16 * 128 + quad * 8;   // A-frag base (m=n16, k=quad*8)

    __syncthreads();   // hS zero + bslots visible

    volatile int* vb = bslots;
    const int myslot = lane & 7;

    for (int c = 0; c < SEQ / CHUNK; c++) {
        const int t0 = c * CHUNK;

        if (l > 0) {
            // once-per-chunk: relaxed spin, then ONE acquire load (buffer_inv)
            const int need = t0 + CHUNK;
            int v = __hip_atomic_load(srcflag, __ATOMIC_RELAXED, __HIP_MEMORY_SCOPE_AGENT);
            while (v < need) {
                __builtin_amdgcn_s_sleep(2);
                v = __hip_atomic_load(srcflag, __ATOMIC_RELAXED, __HIP_MEMORY_SCOPE_AGENT);
            }
            (void)__hip_atomic_load(srcflag, __ATOMIC_ACQUIRE, __HIP_MEMORY_SCOPE_AGENT);
            __asm__ volatile("" ::: "memory");
            const _Float16* hp = hprev + (size_t)t0 * 2048 + hoff;
            #pragma unroll
            for (int kc = 0; kc < 4; kc++) ap[kc] = *(const f16x8*)(hp + kc * 32);
        } else {
            // layer-0: gate on gx window containing reads up to t0+CHUNK
            int wneed = (t0 + CHUNK) >> 6; if (wneed > 7) wneed = 7;
            if (wneed != wcur) {
                int v = __hip_atomic_load(&gxw[wneed], __ATOMIC_RELAXED, __HIP_MEMORY_SCOPE_AGENT);
                while (v < 96) {
                    __builtin_amdgcn_s_sleep(2);
                    v = __hip_atomic_load(&gxw[wneed], __ATOMIC_RELAXED, __HIP_MEMORY_SCOPE_AGENT);
                }
                (void)__hip_atomic_load(&gxw[wneed], __ATOMIC_ACQUIRE, __HIP_MEMORY_SCOPE_AGENT);
                __asm__ volatile("" ::: "memory");
                wcur = wneed;
            }
        }

        #pragma unroll
        for (int i = 0; i < CHUNK; i++) {
            const int t = t0 + i;
            const int sc = t + 1;   // step counter for this barrier

            // ---- distributed-slot flag barrier: no vmcnt drain, pure spin ----
            __asm__ volatile("" ::: "memory");
            if (lane == 0) vb[wv] = sc;
            {
                int v;
                do { v = vb[myslot]; } while (!__all(v >= sc));
            }
            __asm__ volatile("" ::: "memory");

            // issue af LDS reads first (latency overlapped by ih MFMAs below)
            const int rb = (i + CHUNK - 1) & (CHUNK - 1);   // h(t-1) slot
            f16x8 af[4];
            #pragma unroll
            for (int kc = 0; kc < 4; kc++)
                af[kc] = *(const f16x8*)&hS[rb][n16][kc * 32 + quad * 8];

            // ih MFMAs (register inputs, no LDS dependency) — issue first.
            f32x4 ai0 = {0.f, 0.f, 0.f, 0.f}, ai1 = ai0;
            f32x4 ai2 = {bxn, bxn, bxn, bxn};
            if (l > 0) {
                #pragma unroll
                for (int kc = 0; kc < 4; kc++) {
                    ai0 = __builtin_amdgcn_mfma_f32_16x16x32_f16(ap[kc], bi[0][kc], ai0, 0, 0, 0);
                    ai1 = __builtin_amdgcn_mfma_f32_16x16x32_f16(ap[kc], bi[1][kc], ai1, 0, 0, 0);
                    ai2 = __builtin_amdgcn_mfma_f32_16x16x32_f16(ap[kc], bi[2][kc], ai2, 0, 0, 0);
                }
            }

            // EARLY in-chunk prefetch of h_prev(t+1)
            if (l > 0 && i < CHUNK - 1) {
                const _Float16* hp = hprev + (size_t)(t + 1) * 2048 + hoff;
                #pragma unroll
                for (int kc = 0; kc < 4; kc++) ap[kc] = *(const f16x8*)(hp + kc * 32);
            }

            // layer-0: issue gx(t+1) prefetch
            float nr[4], nz[4], nn[4];
            if (l == 0) {
                #pragma unroll
                for (int r = 0; r < 4; r++) {
                    nr[r] = pR[r][0]; nz[r] = pR[r][128]; nn[r] = pR[r][256];
                }
                if (t + 1 < SEQ) {
                    #pragma unroll
                    for (int r = 0; r < 4; r++) pR[r] += G3;
                }
            }

            // hh MFMAs — biases folded into C-init (bcr, bcz, bcn)
            f32x4 ah0 = {bcr, bcr, bcr, bcr};
            f32x4 ah1 = {bcz, bcz, bcz, bcz};
            f32x4 ah2 = {bcn, bcn, bcn, bcn};
            #pragma unroll
            for (int kc = 0; kc < 4; kc++) {
                ah0 = __builtin_amdgcn_mfma_f32_16x16x32_f16(af[kc], bf[0][kc], ah0, 0, 0, 0);
                ah1 = __builtin_amdgcn_mfma_f32_16x16x32_f16(af[kc], bf[1][kc], ah1, 0, 0, 0);
                ah2 = __builtin_amdgcn_mfma_f32_16x16x32_f16(af[kc], bf[2][kc], ah2, 0, 0, 0);
            }

            // finalize: lane owns (m = quad*4+r, j) for all gates
            #pragma unroll
            for (int r = 0; r < 4; r++) {
                const float sxr = (l == 0) ? xr[r] : ai0[r];
                const float sxz = (l == 0) ? xz[r] : ai1[r];
                const float sxn = (l == 0) ? xn[r] : ai2[r];
                const float rg  = sigf(sxr + ah0[r]);
                const float zg  = sigf(sxz + ah1[r]);
                const float th  = tanh_fast(fmaf(rg, ah2[r], sxn));
                const float hnew = fmaf(zg, vhp[r] - th, th);   // (1-z)n + z h
                vhp[r] = hnew;
                hS[i][quad * 4 + r][j] = (_Float16)hnew;        // single h write (ring)
                if (l == 4 && t == SEQ - 1)
                    hlast[(bm0 + quad * 4 + r) * 128 + j] = hnew;
            }

            if (l == 0) {
                #pragma unroll
                for (int r = 0; r < 4; r++) { xr[r] = nr[r]; xz[r] = nz[r]; xn[r] = nn[r]; }
            }
        }

        // ---- chunk boundary (producers only): flush ring -> hmid, RELEASE.
        // l==4 skips entirely (per-step barrier protects ring reuse).
        if (l < 4) {
            __syncthreads();                   // all waves' hS writes visible
            _Float16* dstc = hpub + (size_t)t0 * 2048;
            {
                const int seg0 = tid;            // 0..511
                const int seg1 = tid + 512;
                const int seg2 = tid + 1024;
                const int seg3 = tid + 1536;
                f16x8 v0 = *(const f16x8*)&hS[(seg0 >> 8)][(seg0 >> 4) & 15][(seg0 & 15) * 8];
                f16x8 v1 = *(const f16x8*)&hS[(seg1 >> 8)][(seg1 >> 4) & 15][(seg1 & 15) * 8];
                f16x8 v2 = *(const f16x8*)&hS[(seg2 >> 8)][(seg2 >> 4) & 15][(seg2 & 15) * 8];
                f16x8 v3 = *(const f16x8*)&hS[(seg3 >> 8)][(seg3 >> 4) & 15][(seg3 & 15) * 8];
                *(f16x8*)(dstc + (seg0 >> 4) * 128 + (seg0 & 15) * 8) = v0;
                *(f16x8*)(dstc + (seg1 >> 4) * 128 + (seg1 & 15) * 8) = v1;
                *(f16x8*)(dstc + (seg2 >> 4) * 128 + (seg2 & 15) * 8) = v2;
                *(f16x8*)(dstc + (seg3 >> 4) * 128 + (seg3 & 15) * 8) = v3;
            }
            __syncthreads();                   // drains vmcnt (stores retired)
            if (tid == 0)
                __hip_atomic_store(dstflag, t0 + CHUNK, __ATOMIC_RELEASE, __HIP_MEMORY_SCOPE_AGENT);
        }
    }
}

// ---------------------------------------------------------------------------
// fc: out[b][o] = hlast[b][:] . fc_w[o][:] + fc_b[o]
// ---------------------------------------------------------------------------
__global__ __launch_bounds__(128) void fc_kernel(const float* __restrict__ hlast,
                                                 const float* __restrict__ fc_w,
                                                 const float* __restrict__ fc_b,
                                                 float* __restrict__ out)
{
    const int b = blockIdx.x;
    const int o = threadIdx.x;
    if (o < 96) {
        const float* h = hlast + (size_t)b * HID;
        const float* wrow = fc_w + o * HID;
        float acc = fc_b[o];
        #pragma unroll 4
        for (int k = 0; k < HID; k++) acc = fmaf(h[k], wrow[k], acc);
        out[b * 96 + o] = acc;
    }
}

// ---------------------------------------------------------------------------
extern "C" void kernel_launch(void* const* d_in, const int* in_sizes, int n_in,
                              void* d_out, int out_size, void* d_ws, size_t ws_size,
                              hipStream_t stream)
{
    const float* x         = (const float*)d_in[0]; // [64][512][512]
    const float* w_ih0     = (const float*)d_in[1]; // [384][512]
    const float* w_ih_rest = (const float*)d_in[2]; // [4][384][128]
    const float* w_hh      = (const float*)d_in[3]; // [5][384][128]
    const float* b_ih      = (const float*)d_in[4]; // [5][384]
    const float* b_hh      = (const float*)d_in[5]; // [5][384]
    const float* fc_w      = (const float*)d_in[6]; // [96][128]
    const float* fc_b      = (const float*)d_in[7]; // [96]
    float* out = (float*)d_out;                     // [64][96]

    // workspace layout:
    //   [0,256)              flags (64 ints: [0..15] layer handoff, [16..47] gxdone)
    //   [256, +50331648)     gxbuf fp32 [64][512][384]
    //   [.., +33554432)      hmid  f16  [4][4][512][16][128]
    //   [.., +32768)         hlast fp32 [64][128]
    int*      flags = (int*)d_ws;
    float*    gxbuf = (float*)((char*)d_ws + 256);
    _Float16* hmid  = (_Float16*)((char*)d_ws + 256 + 50331648);
    float*    hlast = (float*)((char*)d_ws + 256 + 50331648 + 33554432);

    hipMemsetAsync(d_ws, 0, 256, stream);

    // ONE launch: blocks 0..19 = gru pipeline (5 layers x 4 batch groups),
    // blocks 20..3091 = gemm producers (t-major: tslot outer, 384 per window)
    gru_fused<<<20 + 3072, 512, 0, stream>>>(x, w_ih0, gxbuf, w_ih_rest, w_hh,
                                             b_ih, b_hh, hmid, hlast, flags);

    fc_kernel<<<BATCH, 128, 0, stream>>>(hlast, fc_w, fc_b, out);
}

// Round 16
// 893.069 us; speedup vs baseline: 1.1724x; 1.0184x over previous
//
#include <hip/hip_runtime.h>
#include <hip/hip_bf16.h>

// Problem constants
#define BATCH   64
#define SEQ     512
#define IN0     512
#define HID     128
#define G3      384   // 3*HID
#define NLAY    5
#define CHUNK   8     // handoff granularity (one release/acquire per CHUNK steps)

typedef _Float16 f16x8 __attribute__((ext_vector_type(8)));
typedef float    f32x4 __attribute__((ext_vector_type(4)));

static __device__ __forceinline__ float sigf(float x) {
    return __builtin_amdgcn_rcpf(1.f + __expf(-x));
}
static __device__ __forceinline__ float tanh_fast(float x) {
    // exp(-2|x|) = exp2(|x| * -2*log2(e)); single mul + v_exp
    const float e = exp2f(fabsf(x) * -2.885390082f);
    return copysignf((1.f - e) * __builtin_amdgcn_rcpf(1.f + e), x);
}

// ---------------------------------------------------------------------------
// gru_fused (R25): R23 structure (35KB smem, 2 blocks/CU — beat R24's 1/CU)
// with the gxdone counters MOVED to their own cacheline region, flags[64..95]
// (bytes 256..383). R23/R24's gru-path inflation diagnosis: 3072 device-scope
// fetch_adds on flags[16..47] FALSE-SHARED the 128B cachelines holding the
// layer-handoff flags[0..15] that every gru block release-stores and
// acquire-polls each chunk -> cross-XCD line ping-pong added ~2-3us/chunk.
// gxbuf shifts to workspace offset 1024; memset widens to 1024 B.
// gru internals = R21 verbatim (slot barrier + pure spin).
// ---------------------------------------------------------------------------
__global__ __launch_bounds__(512, 2) void gru_fused(
    const float* __restrict__ x,          // [64][512][512]
    const float* __restrict__ w_ih0,      // [384][512]
    float* __restrict__ gx,               // gxbuf [32768][384]
    const float* __restrict__ w_ih_rest,  // [4][384][128]
    const float* __restrict__ w_hh,       // [5][384][128]
    const float* __restrict__ b_ih,       // [5][384]
    const float* __restrict__ b_hh,       // [5][384]
    _Float16* __restrict__ hmid,          // [4][4][512][16][128]
    float* __restrict__ hlast,            // [64][128]
    int* __restrict__ flags)              // [0..15] layer handoff | [64..95] gxdone
{
    __shared__ __align__(16) char smem[34848];   // union: gru 34848 B / gemm 10240 B

    const int tid  = threadIdx.x;
    const int lane = tid & 63;
    const int n16  = lane & 15;
    const int quad = lane >> 4;

    if (blockIdx.x >= 20) {
        // ================= gemm role =================
        const int gi    = blockIdx.x - 20;
        const int tslot = gi / 384;          // 0..7  (64-step t window) — t-major
        const int rem   = gi % 384;
        const int bb    = rem / 6;           // batch 0..63
        const int nb    = rem % 6;           // col block 0..5
        const int row0  = bb * 512 + tslot * 64;
        const int col0  = nb * 64;

        _Float16 (*As)[40] = (_Float16(*)[40])smem;            // [64][40]
        _Float16 (*Bs)[40] = (_Float16(*)[40])(smem + 5120);   // [64][40]

        const int wv   = tid >> 6;
        const int msub = wv & 3;             // m-subtile 0..3 (16 rows)
        const int nh   = wv >> 2;            // n-half 0..1 (32 cols)

        f32x4 acc0 = {0.f, 0.f, 0.f, 0.f}, acc1 = acc0;

        // staging: threads 0..255 stage A (x), 256..511 stage B (w_ih0)
        const int half = tid >> 8;
        const int u    = tid & 255;
        const int r    = u >> 2;             // 0..63
        const int kc   = (u & 3) * 8;        // 0,8,16,24
        const float* src0 = (half == 0)
            ? x     + (size_t)(row0 + r) * IN0
            : w_ih0 + (size_t)(col0 + r) * IN0;
        _Float16* dst = (half == 0) ? &As[r][kc] : &Bs[r][kc];

        for (int k0 = 0; k0 < IN0; k0 += 32) {
            float4 a0 = *(const float4*)(src0 + k0 + kc);
            float4 a1 = *(const float4*)(src0 + k0 + kc + 4);
            f16x8 v;
            v[0] = (_Float16)a0.x; v[1] = (_Float16)a0.y; v[2] = (_Float16)a0.z; v[3] = (_Float16)a0.w;
            v[4] = (_Float16)a1.x; v[5] = (_Float16)a1.y; v[6] = (_Float16)a1.z; v[7] = (_Float16)a1.w;
            *(f16x8*)dst = v;
            __syncthreads();
            const f16x8 af  = *(const f16x8*)&As[msub * 16 + n16][quad * 8];
            const f16x8 bf0 = *(const f16x8*)&Bs[nh * 32 + n16][quad * 8];
            const f16x8 bf1 = *(const f16x8*)&Bs[nh * 32 + 16 + n16][quad * 8];
            acc0 = __builtin_amdgcn_mfma_f32_16x16x32_f16(af, bf0, acc0, 0, 0, 0);
            acc1 = __builtin_amdgcn_mfma_f32_16x16x32_f16(af, bf1, acc1, 0, 0, 0);
            __syncthreads();
        }
        // epilogue: bias (layer-0 b_ih) + store
        #pragma unroll
        for (int nt = 0; nt < 2; nt++) {
            const f32x4 a = nt ? acc1 : acc0;
            const int col = col0 + nh * 32 + nt * 16 + n16;
            const float bbias = b_ih[col];
            #pragma unroll
            for (int r4 = 0; r4 < 4; r4++) {
                const int row = row0 + msub * 16 + quad * 4 + r4;
                gx[(size_t)row * G3 + col] = a[r4] + bbias;
            }
        }
        __syncthreads();   // each wave drains its own vmcnt (stores retired)
        if (tid == 0)
            __hip_atomic_fetch_add(&flags[64 + (bb >> 4) * 8 + tslot], 1,
                                   __ATOMIC_RELEASE, __HIP_MEMORY_SCOPE_AGENT);
        return;
    }

    // ================= gru role (R21 internals) =================
    const int l    = blockIdx.x >> 2;
    const int g    = blockIdx.x & 3;
    const int bm0  = g * 16;
    const int wv   = tid >> 6;
    const int j    = wv * 16 + n16;       // hidden index this lane finalizes

    _Float16 (*hS)[16][136] = (_Float16(*)[16][136])smem;   // [8][16][136] ring
    int* bslots = (int*)(smem + 34816);                     // per-wave arrival slots

    // ---- B-frags for w_hh ----
    f16x8 bf[3][4];
    {
        const float* wb = w_hh + (size_t)l * G3 * HID;
        #pragma unroll
        for (int tau = 0; tau < 3; tau++)
            #pragma unroll
            for (int kc = 0; kc < 4; kc++) {
                const float* wp = wb + (size_t)(tau * 128 + j) * HID + kc * 32 + quad * 8;
                f16x8 v;
                #pragma unroll
                for (int i = 0; i < 8; i++) v[i] = (_Float16)wp[i];
                bf[tau][kc] = v;
            }
    }
    // ---- B-frags for w_ih (layers >= 1) ----
    f16x8 bi[3][4];
    if (l > 0) {
        const float* wb = w_ih_rest + (size_t)(l - 1) * G3 * HID;
        #pragma unroll
        for (int tau = 0; tau < 3; tau++)
            #pragma unroll
            for (int kc = 0; kc < 4; kc++) {
                const float* wp = wb + (size_t)(tau * 128 + j) * HID + kc * 32 + quad * 8;
                f16x8 v;
                #pragma unroll
                for (int i = 0; i < 8; i++) v[i] = (_Float16)wp[i];
                bi[tau][kc] = v;
            }
    }
    // gate biases (gx already contains layer-0 b_ih); folded into acc init
    const float bcr = b_hh[l * G3 + j]       + ((l > 0) ? b_ih[l * G3 + j]       : 0.f);
    const float bcz = b_hh[l * G3 + j + 128] + ((l > 0) ? b_ih[l * G3 + j + 128] : 0.f);
    const float bcn = b_hh[l * G3 + j + 256];                      // n-gate: b_hh inside r*(...)
    const float bxn = (l > 0) ? b_ih[l * G3 + j + 256] : 0.f;      // n-gate: b_ih outside

    // ---- zero h ring ----
    for (int i = tid; i < CHUNK * 16 * 136; i += 512) ((_Float16*)hS)[i] = (_Float16)0.f;
    float vhp[4] = {0.f, 0.f, 0.f, 0.f};
    if (tid < 8) bslots[tid] = 0;

    // ---- layer-0: wait gx window 0 (gemm producers), then preload t=0 ----
    const float* pR[4];
    float xr[4], xz[4], xn[4];
    const int* gxw = &flags[64 + g * 8];
    if (l == 0) {
        int v = __hip_atomic_load(&gxw[0], __ATOMIC_RELAXED, __HIP_MEMORY_SCOPE_AGENT);
        while (v < 96) {
            __builtin_amdgcn_s_sleep(2);
            v = __hip_atomic_load(&gxw[0], __ATOMIC_RELAXED, __HIP_MEMORY_SCOPE_AGENT);
        }
        (void)__hip_atomic_load(&gxw[0], __ATOMIC_ACQUIRE, __HIP_MEMORY_SCOPE_AGENT);
        __asm__ volatile("" ::: "memory");
        #pragma unroll
        for (int r = 0; r < 4; r++) {
            pR[r] = gx + (size_t)(bm0 + quad * 4 + r) * SEQ * G3 + j;
            xr[r] = pR[r][0]; xz[r] = pR[r][128]; xn[r] = pR[r][256];
            pR[r] += G3;
        }
    }
    int wcur = 0;

    const _Float16* hprev = (l > 0) ? hmid + (size_t)((l - 1) * 4 + g) * SEQ * 2048 : (const _Float16*)nullptr;
    _Float16*       hpub  = (l < 4) ? hmid + (size_t)(l * 4 + g) * SEQ * 2048 : (_Float16*)nullptr;
    int*       dstflag = (l < 4) ? &flags[l * 4 + g] : (int*)nullptr;
    const int* srcflag = (l > 0) ? &flags[(l - 1) * 4 + g] : (const int*)nullptr;

    f16x8 ap[4];                             // h_prev(t) A-frags
    const int hoff = n16 * 128 + quad * 8;   // A-frag base (m=n16, k=quad*8)

    __syncthreads();   // hS zero + bslots visible

    volatile int* vb = bslots;
    const int myslot = lane & 7;

    for (int c = 0; c < SEQ / CHUNK; c++) {
        const int t0 = c * CHUNK;

        if (l > 0) {
            // once-per-chunk: relaxed spin, then ONE acquire load (buffer_inv)
            const int need = t0 + CHUNK;
            int v = __hip_atomic_load(srcflag, __ATOMIC_RELAXED, __HIP_MEMORY_SCOPE_AGENT);
            while (v < need) {
                __builtin_amdgcn_s_sleep(2);
                v = __hip_atomic_load(srcflag, __ATOMIC_RELAXED, __HIP_MEMORY_SCOPE_AGENT);
            }
            (void)__hip_atomic_load(srcflag, __ATOMIC_ACQUIRE, __HIP_MEMORY_SCOPE_AGENT);
            __asm__ volatile("" ::: "memory");
            const _Float16* hp = hprev + (size_t)t0 * 2048 + hoff;
            #pragma unroll
            for (int kc = 0; kc < 4; kc++) ap[kc] = *(const f16x8*)(hp + kc * 32);
        } else {
            // layer-0: gate on gx window containing reads up to t0+CHUNK
            int wneed = (t0 + CHUNK) >> 6; if (wneed > 7) wneed = 7;
            if (wneed != wcur) {
                int v = __hip_atomic_load(&gxw[wneed], __ATOMIC_RELAXED, __HIP_MEMORY_SCOPE_AGENT);
                while (v < 96) {
                    __builtin_amdgcn_s_sleep(2);
                    v = __hip_atomic_load(&gxw[wneed], __ATOMIC_RELAXED, __HIP_MEMORY_SCOPE_AGENT);
                }
                (void)__hip_atomic_load(&gxw[wneed], __ATOMIC_ACQUIRE, __HIP_MEMORY_SCOPE_AGENT);
                __asm__ volatile("" ::: "memory");
                wcur = wneed;
            }
        }

        #pragma unroll
        for (int i = 0; i < CHUNK; i++) {
            const int t = t0 + i;
            const int sc = t + 1;   // step counter for this barrier

            // ---- distributed-slot flag barrier: no vmcnt drain, pure spin ----
            __asm__ volatile("" ::: "memory");
            if (lane == 0) vb[wv] = sc;
            {
                int v;
                do { v = vb[myslot]; } while (!__all(v >= sc));
            }
            __asm__ volatile("" ::: "memory");

            // issue af LDS reads first (latency overlapped by ih MFMAs below)
            const int rb = (i + CHUNK - 1) & (CHUNK - 1);   // h(t-1) slot
            f16x8 af[4];
            #pragma unroll
            for (int kc = 0; kc < 4; kc++)
                af[kc] = *(const f16x8*)&hS[rb][n16][kc * 32 + quad * 8];

            // ih MFMAs (register inputs, no LDS dependency) — issue first.
            f32x4 ai0 = {0.f, 0.f, 0.f, 0.f}, ai1 = ai0;
            f32x4 ai2 = {bxn, bxn, bxn, bxn};
            if (l > 0) {
                #pragma unroll
                for (int kc = 0; kc < 4; kc++) {
                    ai0 = __builtin_amdgcn_mfma_f32_16x16x32_f16(ap[kc], bi[0][kc], ai0, 0, 0, 0);
                    ai1 = __builtin_amdgcn_mfma_f32_16x16x32_f16(ap[kc], bi[1][kc], ai1, 0, 0, 0);
                    ai2 = __builtin_amdgcn_mfma_f32_16x16x32_f16(ap[kc], bi[2][kc], ai2, 0, 0, 0);
                }
            }

            // EARLY in-chunk prefetch of h_prev(t+1)
            if (l > 0 && i < CHUNK - 1) {
                const _Float16* hp = hprev + (size_t)(t + 1) * 2048 + hoff;
                #pragma unroll
                for (int kc = 0; kc < 4; kc++) ap[kc] = *(const f16x8*)(hp + kc * 32);
            }

            // layer-0: issue gx(t+1) prefetch
            float nr[4], nz[4], nn[4];
            if (l == 0) {
                #pragma unroll
                for (int r = 0; r < 4; r++) {
                    nr[r] = pR[r][0]; nz[r] = pR[r][128]; nn[r] = pR[r][256];
                }
                if (t + 1 < SEQ) {
                    #pragma unroll
                    for (int r = 0; r < 4; r++) pR[r] += G3;
                }
            }

            // hh MFMAs — biases folded into C-init (bcr, bcz, bcn)
            f32x4 ah0 = {bcr, bcr, bcr, bcr};
            f32x4 ah1 = {bcz, bcz, bcz, bcz};
            f32x4 ah2 = {bcn, bcn, bcn, bcn};
            #pragma unroll
            for (int kc = 0; kc < 4; kc++) {
                ah0 = __builtin_amdgcn_mfma_f32_16x16x32_f16(af[kc], bf[0][kc], ah0, 0, 0, 0);
                ah1 = __builtin_amdgcn_mfma_f32_16x16x32_f16(af[kc], bf[1][kc], ah1, 0, 0, 0);
                ah2 = __builtin_amdgcn_mfma_f32_16x16x32_f16(af[kc], bf[2][kc], ah2, 0, 0, 0);
            }

            // finalize: lane owns (m = quad*4+r, j) for all gates
            #pragma unroll
            for (int r = 0; r < 4; r++) {
                const float sxr = (l == 0) ? xr[r] : ai0[r];
                const float sxz = (l == 0) ? xz[r] : ai1[r];
                const float sxn = (l == 0) ? xn[r] : ai2[r];
                const float rg  = sigf(sxr + ah0[r]);
                const float zg  = sigf(sxz + ah1[r]);
                const float th  = tanh_fast(fmaf(rg, ah2[r], sxn));
                const float hnew = fmaf(zg, vhp[r] - th, th);   // (1-z)n + z h
                vhp[r] = hnew;
                hS[i][quad * 4 + r][j] = (_Float16)hnew;        // single h write (ring)
                if (l == 4 && t == SEQ - 1)
                    hlast[(bm0 + quad * 4 + r) * 128 + j] = hnew;
            }

            if (l == 0) {
                #pragma unroll
                for (int r = 0; r < 4; r++) { xr[r] = nr[r]; xz[r] = nz[r]; xn[r] = nn[r]; }
            }
        }

        // ---- chunk boundary (producers only): flush ring -> hmid, RELEASE.
        // l==4 skips entirely (per-step barrier protects ring reuse).
        if (l < 4) {
            __syncthreads();                   // all waves' hS writes visible
            _Float16* dstc = hpub + (size_t)t0 * 2048;
            {
                const int seg0 = tid;            // 0..511
                const int seg1 = tid + 512;
                const int seg2 = tid + 1024;
                const int seg3 = tid + 1536;
                f16x8 v0 = *(const f16x8*)&hS[(seg0 >> 8)][(seg0 >> 4) & 15][(seg0 & 15) * 8];
                f16x8 v1 = *(const f16x8*)&hS[(seg1 >> 8)][(seg1 >> 4) & 15][(seg1 & 15) * 8];
                f16x8 v2 = *(const f16x8*)&hS[(seg2 >> 8)][(seg2 >> 4) & 15][(seg2 & 15) * 8];
                f16x8 v3 = *(const f16x8*)&hS[(seg3 >> 8)][(seg3 >> 4) & 15][(seg3 & 15) * 8];
                *(f16x8*)(dstc + (seg0 >> 4) * 128 + (seg0 & 15) * 8) = v0;
                *(f16x8*)(dstc + (seg1 >> 4) * 128 + (seg1 & 15) * 8) = v1;
                *(f16x8*)(dstc + (seg2 >> 4) * 128 + (seg2 & 15) * 8) = v2;
                *(f16x8*)(dstc + (seg3 >> 4) * 128 + (seg3 & 15) * 8) = v3;
            }
            __syncthreads();                   // drains vmcnt (stores retired)
            if (tid == 0)
                __hip_atomic_store(dstflag, t0 + CHUNK, __ATOMIC_RELEASE, __HIP_MEMORY_SCOPE_AGENT);
        }
    }
}

// ---------------------------------------------------------------------------
// fc: out[b][o] = hlast[b][:] . fc_w[o][:] + fc_b[o]
// ---------------------------------------------------------------------------
__global__ __launch_bounds__(128) void fc_kernel(const float* __restrict__ hlast,
                                                 const float* __restrict__ fc_w,
                                                 const float* __restrict__ fc_b,
                                                 float* __restrict__ out)
{
    const int b = blockIdx.x;
    const int o = threadIdx.x;
    if (o < 96) {
        const float* h = hlast + (size_t)b * HID;
        const float* wrow = fc_w + o * HID;
        float acc = fc_b[o];
        #pragma unroll 4
        for (int k = 0; k < HID; k++) acc = fmaf(h[k], wrow[k], acc);
        out[b * 96 + o] = acc;
    }
}

// ---------------------------------------------------------------------------
extern "C" void kernel_launch(void* const* d_in, const int* in_sizes, int n_in,
                              void* d_out, int out_size, void* d_ws, size_t ws_size,
                              hipStream_t stream)
{
    const float* x         = (const float*)d_in[0]; // [64][512][512]
    const float* w_ih0     = (const float*)d_in[1]; // [384][512]
    const float* w_ih_rest = (const float*)d_in[2]; // [4][384][128]
    const float* w_hh      = (const float*)d_in[3]; // [5][384][128]
    const float* b_ih      = (const float*)d_in[4]; // [5][384]
    const float* b_hh      = (const float*)d_in[5]; // [5][384]
    const float* fc_w      = (const float*)d_in[6]; // [96][128]
    const float* fc_b      = (const float*)d_in[7]; // [96]
    float* out = (float*)d_out;                     // [64][96]

    // workspace layout:
    //   [0,1024)             flags: [0..15] layer handoff (cacheline 0),
    //                        [64..95] gxdone (bytes 256..383 — separate lines)
    //   [1024, +50331648)    gxbuf fp32 [64][512][384]
    //   [.., +33554432)      hmid  f16  [4][4][512][16][128]
    //   [.., +32768)         hlast fp32 [64][128]
    int*      flags = (int*)d_ws;
    float*    gxbuf = (float*)((char*)d_ws + 1024);
    _Float16* hmid  = (_Float16*)((char*)d_ws + 1024 + 50331648);
    float*    hlast = (float*)((char*)d_ws + 1024 + 50331648 + 33554432);

    hipMemsetAsync(d_ws, 0, 1024, stream);

    // ONE launch: blocks 0..19 = gru pipeline (5 layers x 4 batch groups),
    // blocks 20..3091 = gemm producers (t-major: tslot outer, 384 per window)
    gru_fused<<<20 + 3072, 512, 0, stream>>>(x, w_ih0, gxbuf, w_ih_rest, w_hh,
                                             b_ih, b_hh, hmid, hlast, flags);

    fc_kernel<<<BATCH, 128, 0, stream>>>(hlast, fc_w, fc_b, out);
}